// Round 14
// baseline (2774.693 us; speedup 1.0000x reference)
//
#include <hip/hip_runtime.h>
#include <stdint.h>

// SIREN batched MLP, MI355X/gfx950 — round 25: 8 waves/SIMD via LDS eviction.
// r24 reproduced r20: 154.3 us, absmax bit-exact, MfmaUtil 54 = matrix pipe
// busy 83us == theoretical MFMA floor (85us). Pipe runs at peak WHEN FED; it
// idles 46% on epi/LDS latency that 4 waves/SIMD can't cover. VGPR=64 is
// already the 8-wave cap; only LDS (135K -> 1 block/CU) blocks occupancy.
// r25: move W3H/W4H frag images (64KB) to per-batch ws (global), built by a
// tiny prep kernel; LDS 135K -> 71K -> TWO 1024-thr blocks/CU = 8 waves/SIMD.
// Evicted reads = coalesced global_load_dwordx4 (lane l reads frag l);
// distinct data 32 batches x 64KB = 2MB fits in EVERY XCD's 4MB L2;
// demand ~13 TB/s < 34.5 L2 ceiling. L2 latency (~200cy) is what 8
// waves/SIMD hides. Grid (32,16): 512 blocks = 2/CU on all 256 CUs.
// Arithmetic identical to r20/r24 -> absmax must stay 0.009765625 bit-exact.
// Falsifiers: spill signature in WRITE_SIZE or dur>=154 -> revert to r24.

typedef _Float16 f16x8 __attribute__((ext_vector_type(8)));
typedef __fp16 h16x2 __attribute__((ext_vector_type(2)));   // cvt_pkrtz return type
typedef float f32x4 __attribute__((ext_vector_type(4)));

#define MFMA16 __builtin_amdgcn_mfma_f32_16x16x32_f16

#define B_ 32
#define N_ 32768
#define NTHR 1024
#define NWAVE 16
#define OMEGA_SC 4.77464829275686f   /* 30 / (2*pi) */

// flat param offsets (floats)
#define OFF_W1 0
#define OFF_B1 256
#define OFF_W2 384
#define OFF_B2 16768
#define OFF_W3 16896
#define OFF_B3 33280
#define OFF_W4 33408
#define OFF_B4 49792
#define OFF_W5 49920
#define OFF_B5 50304
#define NPARAM 50307

// ws layout (bytes, per batch): W3H/W4H A-frag images [c][mt][lane]*16B
#define WS_L3H 0
#define WS_L4H 32768
#define SWS    65536        /* x32 batches = 2 MB total (fits any XCD L2) */

// LDS image offsets (bytes). A-frag images: [c][mt][lane]*16B.
#define WO_L2H 0
#define WO_W2L 32768
#define WO_L5H 65536       /* 4 KB: single M-tile, rows 3..15 zero */
#define WO_W1X 69632       /* 128 floats, slot-ordered s = c*32 + k_local */
#define WO_W1Y 70144
#define WO_B1S 70656
#define LDS_BIAS 71168     /* 3*128 floats */
#define LDSSET 72704       /* 71 KB -> 2 blocks/CU (142 KB of 160) */

// args arrive pre-scaled by OMEGA_SC (revolutions); v_sin_f32 HW-reduces.
__device__ __forceinline__ float sin_rev(float t) {
    return __builtin_amdgcn_sinf(t);
}

__device__ __forceinline__ uint32_t pkrtz_u32(float a, float b) {
    union { h16x2 v; uint32_t u; } x;
    x.v = __builtin_amdgcn_cvt_pkrtz(a, b);
    return x.u;
}

// sin pair -> hi/lo split packed via pkrtz (lo captures RTZ residual exactly)
__device__ __forceinline__ void sin_split_pk(float a0, float a1,
                                             uint32_t& hw, uint32_t& lw) {
    float s0 = sin_rev(a0), s1 = sin_rev(a1);
    union { h16x2 v; uint32_t u; } x, y;
    x.v = __builtin_amdgcn_cvt_pkrtz(s0, s1);
    float l0 = s0 - (float)x.v[0], l1 = s1 - (float)x.v[1];
    y.v = __builtin_amdgcn_cvt_pkrtz(l0, l1);
    hw = x.u; lw = y.u;
}

// ---------------------------------------------------------------------------
// Prep: build W3H/W4H A-frag images into ws (global). Layout identical to the
// in-LDS images: frag idx = (c*8+mt)*64 + lane, 16 B each, omega-scaled f16 hi.
// ---------------------------------------------------------------------------
__global__ __launch_bounds__(64) void siren_prep(const float* __restrict__ p0,
                                                 char* __restrict__ ws) {
    const int u = blockIdx.x;      // 0..63: [0,32)=W3, [32,64)=W4
    const int b = blockIdx.y;
    const int l = threadIdx.x;
    const float* p = p0 + (size_t)b * NPARAM;

    const int li = (u < 32) ? 1 : 2;
    const int r = u & 31, c = r >> 3, mt = r & 7;
    const int m = l & 15, gA = l >> 4;
    const int wOff = (li == 1) ? OFF_W3 : OFF_W4;
    char* dst = ws + (size_t)b * SWS + ((li == 1) ? WS_L3H : WS_L4H);
    const int j = 16 * mt + m;
    const int f0 = 16 * c + 4 * gA;

    float4 a  = *(const float4*)(p + wOff + j * 128 + f0);
    float4 bq = *(const float4*)(p + wOff + j * 128 + f0 + 64);
    float v[8] = {OMEGA_SC * a.x,  OMEGA_SC * a.y,  OMEGA_SC * a.z,  OMEGA_SC * a.w,
                  OMEGA_SC * bq.x, OMEGA_SC * bq.y, OMEGA_SC * bq.z, OMEGA_SC * bq.w};
    f16x8 hv;
#pragma unroll
    for (int e = 0; e < 8; ++e) hv[e] = (_Float16)v[e];
    *(f16x8*)(dst + (size_t)((c * 8 + mt) * 64 + l) * 16) = hv;
}

// ---------------------------------------------------------------------------
// Main: 1024 threads = 16 waves; 2 blocks/CU -> 8 waves/SIMD (71 KB LDS).
// Phase 0 (fused prep): L2 hi+lo, L5, W1/B1S images into LDS (omega-scaled).
// Phase 1: block covers a 2048-pt slab = 64 tiles; wave w takes tiles
//   w, w+16, w+32, w+48 (4 each). L3/L4 weight frags read from ws (L2-hot).
// Grid (32 batches, 16 slabs).
// ---------------------------------------------------------------------------
__global__ __launch_bounds__(NTHR, 8)
void siren_main(const float* __restrict__ xg,
                const float* __restrict__ pg,
                float* __restrict__ out,
                const char* __restrict__ ws) {
    extern __shared__ __align__(16) char smem[];

    const int t = threadIdx.x;
    const int b = blockIdx.x;
    const int grp = blockIdx.y;
    const float* p = pg + (size_t)b * NPARAM;

    // ---- fused prep: 38 u-slots x 64 lanes, wave-uniform u ----
    for (int it = t; it < 38 * 64; it += NTHR) {
        const int u = it >> 6, l = it & 63;
        if (u < 32) {
            // L2 images, hi + lo
            const int c = u >> 3, mt = u & 7;
            const int m = l & 15, gA = l >> 4;
            const int j = 16 * mt + m;
            const int f0 = 16 * c + 4 * gA;
            float4 a  = *(const float4*)(p + OFF_W2 + j * 128 + f0);
            float4 bq = *(const float4*)(p + OFF_W2 + j * 128 + f0 + 64);
            float v[8] = {OMEGA_SC * a.x,  OMEGA_SC * a.y,  OMEGA_SC * a.z,  OMEGA_SC * a.w,
                          OMEGA_SC * bq.x, OMEGA_SC * bq.y, OMEGA_SC * bq.z, OMEGA_SC * bq.w};
            f16x8 hv, lv;
#pragma unroll
            for (int e = 0; e < 8; ++e) {
                _Float16 hh = (_Float16)v[e];
                hv[e] = hh;
                lv[e] = (_Float16)(v[e] - (float)hh);
            }
            size_t idx = (size_t)((c * 8 + mt) * 64 + l) * 16;
            *(f16x8*)(smem + WO_L2H + idx) = hv;
            *(f16x8*)(smem + WO_W2L + idx) = lv;
        } else if (u < 36) {
            // L5 image (unscaled; rows 3..15 zero)
            const int c = u - 32;
            const int m = l & 15, gA = l >> 4;
            const int f0 = 16 * c + 4 * gA;
            float v[8];
            if (m >= 3) {
#pragma unroll
                for (int e = 0; e < 8; ++e) v[e] = 0.f;
            } else {
                float4 a  = *(const float4*)(p + OFF_W5 + m * 128 + f0);
                float4 bq = *(const float4*)(p + OFF_W5 + m * 128 + f0 + 64);
                v[0] = a.x;  v[1] = a.y;  v[2] = a.z;  v[3] = a.w;
                v[4] = bq.x; v[5] = bq.y; v[6] = bq.z; v[7] = bq.w;
            }
            f16x8 hv;
#pragma unroll
            for (int e = 0; e < 8; ++e) hv[e] = (_Float16)v[e];
            *(f16x8*)(smem + WO_L5H + (size_t)(c * 64 + l) * 16) = hv;
        } else {
            int s = ((u - 36) << 6) + l;       // 0..127
            int c = s >> 5, k = s & 31, gq = k >> 3, e = k & 7;
            int f = 16 * c + ((e & 4) ? 64 : 0) + 4 * gq + (e & 3);
            ((float*)(smem + WO_W1X))[s] = OMEGA_SC * p[OFF_W1 + 2 * f];
            ((float*)(smem + WO_W1Y))[s] = OMEGA_SC * p[OFF_W1 + 2 * f + 1];
            ((float*)(smem + WO_B1S))[s] = OMEGA_SC * p[OFF_B1 + f];
        }
    }
    float* sB = (float*)(smem + LDS_BIAS);
    if (t < 384) {
        int li = t >> 7, f = t & 127;
        sB[t] = OMEGA_SC * p[(li == 0 ? OFF_B2 : li == 1 ? OFF_B3 : OFF_B4) + f];
    }
    const float b5_0 = p[OFF_B5], b5_1 = p[OFF_B5 + 1], b5_2 = p[OFF_B5 + 2];
    __syncthreads();

    const int lane = t & 63;
    const int wv = t >> 6;          // 0..15
    const int n = lane & 15;
    const int g = lane >> 4;
    const int lb = lane * 16;

    const char* L2Hp = smem + WO_L2H;
    const char* W2Lp = smem + WO_W2L;
    const char* L5Hp = smem + WO_L5H;
    const float* W1X = (const float*)(smem + WO_W1X);
    const float* W1Y = (const float*)(smem + WO_W1Y);
    const float* B1S = (const float*)(smem + WO_B1S);

    // L3/L4 frag images in global (L2-cache-hot): frag idx (c*8+mt)*64 + lane
    const f16x8* __restrict__ W3g = (const f16x8*)(ws + (size_t)b * SWS + WS_L3H);
    const f16x8* __restrict__ W4g = (const f16x8*)(ws + (size_t)b * SWS + WS_L4H);

    union UF { f16x8 v; uint32_t w[4]; };

    auto initb2 = [&](f32x4 (&A)[2][8], int li) {
#pragma unroll
        for (int mt = 0; mt < 8; ++mt) {
            f32x4 bb = *(const f32x4*)&sB[li * 128 + 16 * mt + 4 * g];
            A[0][mt] = bb;
            A[1][mt] = bb;
        }
    };

    // acc -> B-frag chunk c; pair-convert+pack in ONE v_cvt_pkrtz_f16_f32
    auto epi_hi2 = [&](const f32x4 (&A)[2][8], UF (&Xh)[2][4]) {
#pragma unroll
        for (int pp = 0; pp < 2; ++pp)
#pragma unroll
            for (int c = 0; c < 4; ++c) {
                float s[8];
#pragma unroll
                for (int r = 0; r < 4; ++r) {
                    s[r]     = sin_rev(A[pp][c][r]);
                    s[4 + r] = sin_rev(A[pp][c + 4][r]);
                }
                Xh[pp][c].w[0] = pkrtz_u32(s[0], s[1]);
                Xh[pp][c].w[1] = pkrtz_u32(s[2], s[3]);
                Xh[pp][c].w[2] = pkrtz_u32(s[4], s[5]);
                Xh[pp][c].w[3] = pkrtz_u32(s[6], s[7]);
            }
    };

#pragma unroll 1
    for (int tile = wv; tile < 64; tile += NWAVE) {
        const int ptb = grp * 2048 + tile * 32;
        const float2 xy0 = ((const float2*)xg)[(size_t)b * N_ + ptb + n];
        const float2 xy1 = ((const float2*)xg)[(size_t)b * N_ + ptb + 16 + n];

        // ---- L1+L2 fused per c-chunk: produce X1h/l[.][c], consume in L2
        f32x4 A2[2][8];
        initb2(A2, 0);
#pragma unroll
        for (int c = 0; c < 4; ++c) {
            UF X1h[2], X1l[2];
            {
                const int s0 = c * 32 + g * 8;
                float4 wxa = *(const float4*)(W1X + s0), wxb = *(const float4*)(W1X + s0 + 4);
                float4 wya = *(const float4*)(W1Y + s0), wyb = *(const float4*)(W1Y + s0 + 4);
                float4 bba = *(const float4*)(B1S + s0), bbb = *(const float4*)(B1S + s0 + 4);
                float wx[8] = {wxa.x, wxa.y, wxa.z, wxa.w, wxb.x, wxb.y, wxb.z, wxb.w};
                float wy[8] = {wya.x, wya.y, wya.z, wya.w, wyb.x, wyb.y, wyb.z, wyb.w};
                float bc[8] = {bba.x, bba.y, bba.z, bba.w, bbb.x, bbb.y, bbb.z, bbb.w};
#pragma unroll
                for (int pp = 0; pp < 2; ++pp) {
                    const float px = pp ? xy1.x : xy0.x;
                    const float py = pp ? xy1.y : xy0.y;
                    float a[8];
#pragma unroll
                    for (int e = 0; e < 8; ++e)
                        a[e] = fmaf(px, wx[e], fmaf(py, wy[e], bc[e]));
                    sin_split_pk(a[0], a[1], X1h[pp].w[0], X1l[pp].w[0]);
                    sin_split_pk(a[2], a[3], X1h[pp].w[1], X1l[pp].w[1]);
                    sin_split_pk(a[4], a[5], X1h[pp].w[2], X1l[pp].w[2]);
                    sin_split_pk(a[6], a[7], X1h[pp].w[3], X1l[pp].w[3]);
                }
            }
            __builtin_amdgcn_s_setprio(1);
#pragma unroll
            for (int mt = 0; mt < 8; ++mt) {
                f16x8 ah = *(const f16x8*)(L2Hp + (c * 8 + mt) * 1024 + lb);
                f16x8 al = *(const f16x8*)(W2Lp + (c * 8 + mt) * 1024 + lb);
#pragma unroll
                for (int pp = 0; pp < 2; ++pp) {
                    A2[pp][mt] = MFMA16(ah, X1h[pp].v, A2[pp][mt], 0, 0, 0);
                    A2[pp][mt] = MFMA16(ah, X1l[pp].v, A2[pp][mt], 0, 0, 0);
                    A2[pp][mt] = MFMA16(al, X1h[pp].v, A2[pp][mt], 0, 0, 0);
                }
            }
            __builtin_amdgcn_s_setprio(0);
        }

        UF X2h[2][4];
        epi_hi2(A2, X2h);

        // ---- L3: frags from global (XCD-L2-resident)
        f32x4 A3[2][8];
        initb2(A3, 1);
        __builtin_amdgcn_s_setprio(1);
#pragma unroll
        for (int c = 0; c < 4; ++c)
#pragma unroll
            for (int mt = 0; mt < 8; ++mt) {
                f16x8 ah = W3g[(c * 8 + mt) * 64 + lane];
#pragma unroll
                for (int pp = 0; pp < 2; ++pp)
                    A3[pp][mt] = MFMA16(ah, X2h[pp][c].v, A3[pp][mt], 0, 0, 0);
            }
        __builtin_amdgcn_s_setprio(0);

        UF X3h[2][4];
        epi_hi2(A3, X3h);

        // ---- L4: frags from global (XCD-L2-resident)
        f32x4 A4[2][8];
        initb2(A4, 2);
        __builtin_amdgcn_s_setprio(1);
#pragma unroll
        for (int c = 0; c < 4; ++c)
#pragma unroll
            for (int mt = 0; mt < 8; ++mt) {
                f16x8 ah = W4g[(c * 8 + mt) * 64 + lane];
#pragma unroll
                for (int pp = 0; pp < 2; ++pp)
                    A4[pp][mt] = MFMA16(ah, X3h[pp][c].v, A4[pp][mt], 0, 0, 0);
            }
        __builtin_amdgcn_s_setprio(0);

        UF X4h[2][4];
        epi_hi2(A4, X4h);

        // ---- L5: single M-padded tile per point-tile (LDS)
        f32x4 a5[2] = {{0.f, 0.f, 0.f, 0.f}, {0.f, 0.f, 0.f, 0.f}};
        __builtin_amdgcn_s_setprio(1);
#pragma unroll
        for (int c = 0; c < 4; ++c) {
            f16x8 ah = *(const f16x8*)(L5Hp + c * 1024 + lb);
#pragma unroll
            for (int pp = 0; pp < 2; ++pp)
                a5[pp] = MFMA16(ah, X4h[pp][c].v, a5[pp], 0, 0, 0);
        }
        __builtin_amdgcn_s_setprio(0);

        if (g == 0) {   // rows 0..2 = outputs j=0..2 for point n
#pragma unroll
            for (int pp = 0; pp < 2; ++pp) {
                size_t o = ((size_t)b * N_ + ptb + pp * 16 + n) * 3;
                out[o]     = a5[pp][0] + b5_0;
                out[o + 1] = a5[pp][1] + b5_1;
                out[o + 2] = a5[pp][2] + b5_2;
            }
        }
    }
}

extern "C" void kernel_launch(void* const* d_in, const int* in_sizes, int n_in,
                              void* d_out, int out_size, void* d_ws, size_t ws_size,
                              hipStream_t stream) {
    (void)in_sizes; (void)n_in; (void)out_size; (void)ws_size;
    const float* x = (const float*)d_in[0];
    const float* p = (const float*)d_in[1];
    float* o = (float*)d_out;
    char* ws = (char*)d_ws;   // needs 32 * 65536 = 2,097,152 B

    // Raise the dynamic-LDS cap exactly once (not per graph-capture pass).
    static bool attr_done = false;
    if (!attr_done) {
        (void)hipFuncSetAttribute(reinterpret_cast<const void*>(siren_main),
                                  hipFuncAttributeMaxDynamicSharedMemorySize, LDSSET);
        attr_done = true;
    }
    siren_prep<<<dim3(64, 32), 64, 0, stream>>>(p, ws);
    siren_main<<<dim3(32, 16), NTHR, LDSSET, stream>>>(x, p, o, ws);
}

// Round 15
// 198.569 us; speedup vs baseline: 13.9734x; 13.9734x over previous
//
#include <hip/hip_runtime.h>
#include <stdint.h>

// SIREN batched MLP, MI355X/gfx950 — round 26: restore exact r24 (verified best).
// r25 post-mortem: launch_bounds(1024,8) caps 64 regs/wave < irreducible
// working set (~128: 64 acc + frags) -> accumulators spilled to scratch ->
// 6.3 GB writes, 2743 us. r24's VGPR=64 is arch-VGPRs; ~64 more live in AGPRs
// -> true working set == 4-wave cap EXACTLY. Occupancy axis closed.
// Full ledger of closed axes: hand-skew (r17), <3-term L2 (r19), 32x32 MFMA
// (r21/22), +reg state (r23), 8 waves/SIMD (r25). r24 = 154.3 us, matrix-pipe
// busy (83us) == MFMA floor (85us): pipe at peak when fed; feeding levers
// exhausted. This file is byte-equivalent to r24.
// Numerics: L1 fp32+split, L2 3-term hi/lo, L3/L4/L5 hi-only, pkrtz epi,
// omega folded into staged W1..W4/b1..b4, no v_fract, no cross-iter barrier.
// Expected: dispatch ~154.3 us, absmax bit-exact 0.009765625.

typedef _Float16 f16x8 __attribute__((ext_vector_type(8)));
typedef __fp16 h16x2 __attribute__((ext_vector_type(2)));   // cvt_pkrtz return type
typedef float f32x4 __attribute__((ext_vector_type(4)));

#define MFMA16 __builtin_amdgcn_mfma_f32_16x16x32_f16

#define B_ 32
#define N_ 32768
#define NTHR 1024
#define NWAVE 16
#define OMEGA_SC 4.77464829275686f   /* 30 / (2*pi) */

// flat param offsets (floats)
#define OFF_W1 0
#define OFF_B1 256
#define OFF_W2 384
#define OFF_B2 16768
#define OFF_W3 16896
#define OFF_B3 33280
#define OFF_W4 33408
#define OFF_B4 49792
#define OFF_W5 49920
#define OFF_B5 50304
#define NPARAM 50307

// LDS image offsets (bytes). A-frag images: [c][mt][lane]*16B.
#define WO_L2H 0
#define WO_W2L 32768
#define WO_L3H 65536
#define WO_L4H 98304
#define WO_L5H 131072      /* 4 KB: single M-tile, rows 3..15 zero */
#define WO_W1X 135168      /* 128 floats, slot-ordered s = c*32 + k_local */
#define WO_W1Y 135680
#define WO_B1S 136192
#define LDS_BIAS 136704    /* 3*128 floats */
#define LDSSET 138240

// args arrive pre-scaled by OMEGA_SC (revolutions); v_sin_f32 HW-reduces.
__device__ __forceinline__ float sin_rev(float t) {
    return __builtin_amdgcn_sinf(t);
}

__device__ __forceinline__ uint32_t pkrtz_u32(float a, float b) {
    union { h16x2 v; uint32_t u; } x;
    x.v = __builtin_amdgcn_cvt_pkrtz(a, b);
    return x.u;
}

// sin pair -> hi/lo split packed via pkrtz (lo captures RTZ residual exactly)
__device__ __forceinline__ void sin_split_pk(float a0, float a1,
                                             uint32_t& hw, uint32_t& lw) {
    float s0 = sin_rev(a0), s1 = sin_rev(a1);
    union { h16x2 v; uint32_t u; } x, y;
    x.v = __builtin_amdgcn_cvt_pkrtz(s0, s1);
    float l0 = s0 - (float)x.v[0], l1 = s1 - (float)x.v[1];
    y.v = __builtin_amdgcn_cvt_pkrtz(l0, l1);
    hw = x.u; lw = y.u;
}

// ---------------------------------------------------------------------------
// Main: 1024 threads = 16 waves = 4 waves/SIMD, 1 block/CU (135 KB LDS).
// Phase 0 (fused prep): build LDS weight images directly from p, pre-scaled
//   by OMEGA_SC for the sine layers (W1..W4, b1..b4); W5/b5 unscaled.
//   16x16x32 A-frag: lane l holds A[m=16mt+(l&15)][k_local=8*(l>>4)+e];
//   feature f = 16c + 64*(e>=4) + 4g + (e&3). W2 stored hi+lo; W3/4/5 hi only.
// Phase 1: block covers a 4096-pt slab = 128 32-pt tiles; wave w takes tiles
//   w, w+16, ... (8 tiles each). Grid (32 batches, 8 slabs).
// ---------------------------------------------------------------------------
__global__ __launch_bounds__(NTHR, 4)
void siren_main(const float* __restrict__ xg,
                const float* __restrict__ pg,
                float* __restrict__ out) {
    extern __shared__ __align__(16) char smem[];

    const int t = threadIdx.x;
    const int b = blockIdx.x;
    const int grp = blockIdx.y;
    const float* p = pg + (size_t)b * NPARAM;

    // ---- fused prep: 102 u-slots x 64 lanes = 6528 items, wave-uniform u ----
    for (int it = t; it < 6528; it += NTHR) {
        const int u = it >> 6, l = it & 63;
        if (u < 100) {
            int li, c, mt;
            if (u < 96) { li = u >> 5; int r = u & 31; c = r >> 3; mt = r & 7; }
            else        { li = 3; c = u - 96; mt = 0; }
            const int m = l & 15, gA = l >> 4;
            int wOff; size_t dstH; bool lo = false;
            if (li == 0)      { wOff = OFF_W2; dstH = WO_L2H; lo = true; }
            else if (li == 1) { wOff = OFF_W3; dstH = WO_L3H; }
            else if (li == 2) { wOff = OFF_W4; dstH = WO_L4H; }
            else              { wOff = OFF_W5; dstH = WO_L5H; }
            const int j = (li == 3) ? m : (16 * mt + m);
            const int f0 = 16 * c + 4 * gA;
            const float sc = (li == 3) ? 1.0f : OMEGA_SC;   // W5 feeds no sine

            float v[8];
            if (li == 3 && m >= 3) {
#pragma unroll
                for (int e = 0; e < 8; ++e) v[e] = 0.f;
            } else {
                float4 a  = *(const float4*)(p + wOff + j * 128 + f0);
                float4 bq = *(const float4*)(p + wOff + j * 128 + f0 + 64);
                v[0] = sc * a.x;  v[1] = sc * a.y;  v[2] = sc * a.z;  v[3] = sc * a.w;
                v[4] = sc * bq.x; v[5] = sc * bq.y; v[6] = sc * bq.z; v[7] = sc * bq.w;
            }
            f16x8 hv, lv;
#pragma unroll
            for (int e = 0; e < 8; ++e) {
                _Float16 hh = (_Float16)v[e];
                hv[e] = hh;
                lv[e] = (_Float16)(v[e] - (float)hh);
            }
            size_t idx = (li == 3) ? (size_t)(c * 64 + l) * 16
                                   : (size_t)((c * 8 + mt) * 64 + l) * 16;
            *(f16x8*)(smem + dstH + idx) = hv;
            if (lo) *(f16x8*)(smem + WO_W2L + idx) = lv;
        } else {
            int s = ((u - 100) << 6) + l;      // 0..127
            int c = s >> 5, k = s & 31, gq = k >> 3, e = k & 7;
            int f = 16 * c + ((e & 4) ? 64 : 0) + 4 * gq + (e & 3);
            ((float*)(smem + WO_W1X))[s] = OMEGA_SC * p[OFF_W1 + 2 * f];
            ((float*)(smem + WO_W1Y))[s] = OMEGA_SC * p[OFF_W1 + 2 * f + 1];
            ((float*)(smem + WO_B1S))[s] = OMEGA_SC * p[OFF_B1 + f];
        }
    }
    float* sB = (float*)(smem + LDS_BIAS);
    if (t < 384) {
        int li = t >> 7, f = t & 127;
        sB[t] = OMEGA_SC * p[(li == 0 ? OFF_B2 : li == 1 ? OFF_B3 : OFF_B4) + f];
    }
    const float b5_0 = p[OFF_B5], b5_1 = p[OFF_B5 + 1], b5_2 = p[OFF_B5 + 2];
    __syncthreads();

    const int lane = t & 63;
    const int wv = t >> 6;          // 0..15
    const int n = lane & 15;
    const int g = lane >> 4;
    const int lb = lane * 16;

    const char* L2Hp = smem + WO_L2H;
    const char* W2Lp = smem + WO_W2L;
    const char* L3Hp = smem + WO_L3H;
    const char* L4Hp = smem + WO_L4H;
    const char* L5Hp = smem + WO_L5H;
    const float* W1X = (const float*)(smem + WO_W1X);
    const float* W1Y = (const float*)(smem + WO_W1Y);
    const float* B1S = (const float*)(smem + WO_B1S);

    union UF { f16x8 v; uint32_t w[4]; };

    auto initb2 = [&](f32x4 (&A)[2][8], int li) {
#pragma unroll
        for (int mt = 0; mt < 8; ++mt) {
            f32x4 bb = *(const f32x4*)&sB[li * 128 + 16 * mt + 4 * g];
            A[0][mt] = bb;
            A[1][mt] = bb;
        }
    };

    // acc -> B-frag chunk c = {tile c regs 0-3 (e0-3), tile c+4 regs 0-3 (e4-7)}
    // pair-convert+pack in ONE v_cvt_pkrtz_f16_f32 (RTZ)
    auto epi_hi2 = [&](const f32x4 (&A)[2][8], UF (&Xh)[2][4]) {
#pragma unroll
        for (int pp = 0; pp < 2; ++pp)
#pragma unroll
            for (int c = 0; c < 4; ++c) {
                float s[8];
#pragma unroll
                for (int r = 0; r < 4; ++r) {
                    s[r]     = sin_rev(A[pp][c][r]);
                    s[4 + r] = sin_rev(A[pp][c + 4][r]);
                }
                Xh[pp][c].w[0] = pkrtz_u32(s[0], s[1]);
                Xh[pp][c].w[1] = pkrtz_u32(s[2], s[3]);
                Xh[pp][c].w[2] = pkrtz_u32(s[4], s[5]);
                Xh[pp][c].w[3] = pkrtz_u32(s[6], s[7]);
            }
    };

#pragma unroll 1
    for (int tile = wv; tile < 128; tile += NWAVE) {
        const int ptb = grp * 4096 + tile * 32;
        const float2 xy0 = ((const float2*)xg)[(size_t)b * N_ + ptb + n];
        const float2 xy1 = ((const float2*)xg)[(size_t)b * N_ + ptb + 16 + n];

        // ---- L1+L2 fused per c-chunk (r16): produce X1h/l[.][c], consume in
        //      L2 c-pass; L1(c+1) VALU interleaves with in-flight MFMA(c).
        f32x4 A2[2][8];
        initb2(A2, 0);
#pragma unroll
        for (int c = 0; c < 4; ++c) {
            UF X1h[2], X1l[2];
            {
                const int s0 = c * 32 + g * 8;
                float4 wxa = *(const float4*)(W1X + s0), wxb = *(const float4*)(W1X + s0 + 4);
                float4 wya = *(const float4*)(W1Y + s0), wyb = *(const float4*)(W1Y + s0 + 4);
                float4 bba = *(const float4*)(B1S + s0), bbb = *(const float4*)(B1S + s0 + 4);
                float wx[8] = {wxa.x, wxa.y, wxa.z, wxa.w, wxb.x, wxb.y, wxb.z, wxb.w};
                float wy[8] = {wya.x, wya.y, wya.z, wya.w, wyb.x, wyb.y, wyb.z, wyb.w};
                float bc[8] = {bba.x, bba.y, bba.z, bba.w, bbb.x, bbb.y, bbb.z, bbb.w};
#pragma unroll
                for (int pp = 0; pp < 2; ++pp) {
                    const float px = pp ? xy1.x : xy0.x;
                    const float py = pp ? xy1.y : xy0.y;
                    float a[8];
#pragma unroll
                    for (int e = 0; e < 8; ++e)
                        a[e] = fmaf(px, wx[e], fmaf(py, wy[e], bc[e]));
                    sin_split_pk(a[0], a[1], X1h[pp].w[0], X1l[pp].w[0]);
                    sin_split_pk(a[2], a[3], X1h[pp].w[1], X1l[pp].w[1]);
                    sin_split_pk(a[4], a[5], X1h[pp].w[2], X1l[pp].w[2]);
                    sin_split_pk(a[6], a[7], X1h[pp].w[3], X1l[pp].w[3]);
                }
            }
            __builtin_amdgcn_s_setprio(1);
#pragma unroll
            for (int mt = 0; mt < 8; ++mt) {
                f16x8 ah = *(const f16x8*)(L2Hp + (c * 8 + mt) * 1024 + lb);
                f16x8 al = *(const f16x8*)(W2Lp + (c * 8 + mt) * 1024 + lb);
#pragma unroll
                for (int pp = 0; pp < 2; ++pp) {
                    A2[pp][mt] = MFMA16(ah, X1h[pp].v, A2[pp][mt], 0, 0, 0);
                    A2[pp][mt] = MFMA16(ah, X1l[pp].v, A2[pp][mt], 0, 0, 0);
                    A2[pp][mt] = MFMA16(al, X1h[pp].v, A2[pp][mt], 0, 0, 0);
                }
            }
            __builtin_amdgcn_s_setprio(0);
        }

        UF X2h[2][4];
        epi_hi2(A2, X2h);

        // ---- L3: 1-term (X2 hi only)
        f32x4 A3[2][8];
        initb2(A3, 1);
        __builtin_amdgcn_s_setprio(1);
#pragma unroll
        for (int c = 0; c < 4; ++c)
#pragma unroll
            for (int mt = 0; mt < 8; ++mt) {
                f16x8 ah = *(const f16x8*)(L3Hp + (c * 8 + mt) * 1024 + lb);
#pragma unroll
                for (int pp = 0; pp < 2; ++pp)
                    A3[pp][mt] = MFMA16(ah, X2h[pp][c].v, A3[pp][mt], 0, 0, 0);
            }
        __builtin_amdgcn_s_setprio(0);

        UF X3h[2][4];
        epi_hi2(A3, X3h);

        // ---- L4: plain f16
        f32x4 A4[2][8];
        initb2(A4, 2);
        __builtin_amdgcn_s_setprio(1);
#pragma unroll
        for (int c = 0; c < 4; ++c)
#pragma unroll
            for (int mt = 0; mt < 8; ++mt) {
                f16x8 ah = *(const f16x8*)(L4Hp + (c * 8 + mt) * 1024 + lb);
#pragma unroll
                for (int pp = 0; pp < 2; ++pp)
                    A4[pp][mt] = MFMA16(ah, X3h[pp][c].v, A4[pp][mt], 0, 0, 0);
            }
        __builtin_amdgcn_s_setprio(0);

        UF X4h[2][4];
        epi_hi2(A4, X4h);

        // ---- L5: single M-padded tile per point-tile (unscaled weights)
        f32x4 a5[2] = {{0.f, 0.f, 0.f, 0.f}, {0.f, 0.f, 0.f, 0.f}};
        __builtin_amdgcn_s_setprio(1);
#pragma unroll
        for (int c = 0; c < 4; ++c) {
            f16x8 ah = *(const f16x8*)(L5Hp + c * 1024 + lb);
#pragma unroll
            for (int pp = 0; pp < 2; ++pp)
                a5[pp] = MFMA16(ah, X4h[pp][c].v, a5[pp], 0, 0, 0);
        }
        __builtin_amdgcn_s_setprio(0);

        if (g == 0) {   // rows 0..2 = outputs j=0..2 for point n
#pragma unroll
            for (int pp = 0; pp < 2; ++pp) {
                size_t o = ((size_t)b * N_ + ptb + pp * 16 + n) * 3;
                out[o]     = a5[pp][0] + b5_0;
                out[o + 1] = a5[pp][1] + b5_1;
                out[o + 2] = a5[pp][2] + b5_2;
            }
        }
    }
}

extern "C" void kernel_launch(void* const* d_in, const int* in_sizes, int n_in,
                              void* d_out, int out_size, void* d_ws, size_t ws_size,
                              hipStream_t stream) {
    (void)in_sizes; (void)n_in; (void)out_size; (void)d_ws; (void)ws_size;
    const float* x = (const float*)d_in[0];
    const float* p = (const float*)d_in[1];
    float* o = (float*)d_out;

    // Raise the dynamic-LDS cap exactly once (not per graph-capture pass).
    static bool attr_done = false;
    if (!attr_done) {
        (void)hipFuncSetAttribute(reinterpret_cast<const void*>(siren_main),
                                  hipFuncAttributeMaxDynamicSharedMemorySize, LDSSET);
        attr_done = true;
    }
    siren_main<<<dim3(32, 8), NTHR, LDSSET, stream>>>(x, p, o);
}